// Round 6
// baseline (263.471 us; speedup 1.0000x reference)
//
#include <hip/hip_runtime.h>
#include <hip/hip_bf16.h>
#include <cmath>

#define H 256
#define W 256
#define NIMG 64
#define HW 65536
#define NSTRIP 64          // strips per image (2 parities x 32 groups... = 64)
#define TOTSTRIP (NIMG * NSTRIP)   // 4096

// ---------- reduction helpers (wave64) ----------
__device__ inline float waveReduceSum(float v) {
#pragma unroll
    for (int o = 32; o > 0; o >>= 1) v += __shfl_xor(v, o, 64);
    return v;
}
__device__ inline float waveReduceMax(float v) {
#pragma unroll
    for (int o = 32; o > 0; o >>= 1) v = fmaxf(v, __shfl_xor(v, o, 64));
    return v;
}
__device__ inline float blockReduceSum(float v, float* s) {
    int lane = threadIdx.x & 63, wv = threadIdx.x >> 6;
    v = waveReduceSum(v);
    if (lane == 0) s[wv] = v;
    __syncthreads();
    float r = 0.f;
    if (wv == 0) {
        r = (lane < 4) ? s[lane] : 0.f;
        r = waveReduceSum(r);
    }
    __syncthreads();
    return r;
}

__device__ inline float4 sig4(float4 x) {
    float4 s;
    s.x = __builtin_amdgcn_rcpf(1.f + __expf(-x.x));
    s.y = __builtin_amdgcn_rcpf(1.f + __expf(-x.y));
    s.z = __builtin_amdgcn_rcpf(1.f + __expf(-x.z));
    s.w = __builtin_amdgcn_rcpf(1.f + __expf(-x.w));
    return s;
}

// ---------- kernel A: pairwise partials + all row/col maxes ----------
// Wave-per-strip, rolling 3-row register window (rows h-2, h, h+2 share parity),
// zero LDS, zero barriers. sim product identity: one log per pixel (validated R5).
__global__ __launch_bounds__(256) void k_pairwise(
    const float* __restrict__ src, const float* __restrict__ ts,
    const int* __restrict__ bm,
    float* __restrict__ part_st, float* __restrict__ part_t,
    float* __restrict__ rowsig, float* __restrict__ rowmax_b,
    float* __restrict__ colpart_s, float* __restrict__ colpart_b)
{
    const int t = threadIdx.x, lane = t & 63, wv = t >> 6;
    const int strip = blockIdx.x * 4 + wv;          // 0..4095
    const int n = strip >> 6, sid = strip & 63;
    const int parity = sid & 1, g = sid >> 1;       // g in 0..31
    const int h0 = g * 8 + parity;                  // rows h0, h0+2, h0+4, h0+6
    const int c0 = lane << 2;
    const int lm = (lane + 63) & 63, lp = (lane + 1) & 63;

    const float* srcn = src + (size_t)n * HW;
    const int*   bmn  = bm  + (size_t)n * HW;
    const float* tsn  = ts  + (size_t)n * 8 * HW;

    // load raw src row (wave-uniform row index; OOB -> 0 -> sigmoid 0.5, masked later)
    auto loadRaw = [&](int r) -> float4 {
        float4 x = make_float4(0.f, 0.f, 0.f, 0.f);
        if (r >= 0 && r < H) x = *reinterpret_cast<const float4*>(srcn + r * W + c0);
        return x;
    };
    // finish: sigmoid + edge shuffles -> 8-float window row (cols c0-2 .. c0+5)
    auto finishRow = [&](float4 x, float* o) {
        float4 s = sig4(x);
        o[2] = s.x; o[3] = s.y; o[4] = s.z; o[5] = s.w;
        o[0] = __shfl(s.z, lm, 64);   // col c0-2 (lane-1's .z)
        o[1] = __shfl(s.w, lm, 64);   // col c0-1
        o[6] = __shfl(s.x, lp, 64);   // col c0+4
        o[7] = __shfl(s.y, lp, 64);   // col c0+5
    };

    float A[8], B[8], C[8];
    finishRow(loadRaw(h0 - 2), A);
    finishRow(loadRaw(h0),     B);
    finishRow(loadRaw(h0 + 2), C);

    float st = 0.f, tt = 0.f;
    float cms[4] = {0.f, 0.f, 0.f, 0.f};
    float cmb[4] = {0.f, 0.f, 0.f, 0.f};

#pragma unroll
    for (int j = 0; j < 4; j++) {
        const int h = h0 + 2 * j;
        const bool rvt = (h - 2) >= 0;
        const bool rvb = (h + 2) < H;

        // issue all global loads for this row + prefetch next window row first
        const int4 bi = *reinterpret_cast<const int4*>(bmn + h * W + c0);
        float4 tv[8];
#pragma unroll
        for (int p = 0; p < 8; p++)
            tv[p] = *reinterpret_cast<const float4*>(tsn + (size_t)p * HW + h * W + c0);
        float4 nxtraw = make_float4(0.f, 0.f, 0.f, 0.f);
        if (j < 3) nxtraw = loadRaw(h + 4);

        const float* tvp = reinterpret_cast<const float*>(tv);
        float msc = 0.f, mb = 0.f;
#pragma unroll
        for (int p = 0; p < 4; p++) {
            const float sc = B[2 + p];
            const float a2 = 2.f * sc;
            const float b2 = 1.f - sc;
            const float bmf = (float)reinterpret_cast<const int*>(&bi)[p];
            const bool cl = (c0 + p - 2) >= 0;
            const bool cr = (c0 + p + 2) < W;
            msc = fmaxf(msc, sc); mb = fmaxf(mb, bmf);
            cms[p] = fmaxf(cms[p], sc); cmb[p] = fmaxf(cmb[p], bmf);

            float prod = 1.f, cnt = 0.f;
            auto tap = [&](float sn, bool valid, float tsv) {
                const bool thr = (tsv >= 0.3f);
                cnt += thr ? 1.f : 0.f;                  // padded taps still count in tgt
                const float P = fmaf(a2, sn, b2 - sn);   // sc*sn + (1-sc)(1-sn)
                prod *= (thr && valid) ? P : 1.f;
            };
            // unfold order (i-major, j-minor, center removed); A[i]=col c0+i-2
            tap(A[p],     rvt && cl, tvp[0 * 4 + p]);
            tap(A[2 + p], rvt,       tvp[1 * 4 + p]);
            tap(A[4 + p], rvt && cr, tvp[2 * 4 + p]);
            tap(B[p],     cl,        tvp[3 * 4 + p]);
            tap(B[4 + p], cr,        tvp[4 * 4 + p]);
            tap(C[p],     rvb && cl, tvp[5 * 4 + p]);
            tap(C[2 + p], rvb,       tvp[6 * 4 + p]);
            tap(C[4 + p], rvb && cr, tvp[7 * 4 + p]);

            st = fmaf(bmf, -__logf(prod), st);   // one log per pixel
            tt = fmaf(bmf, cnt, tt);
        }
        // per-row maxes: wave owns the row -> pure wave reduce
        const float wms = waveReduceMax(msc);
        const float wmb = waveReduceMax(mb);
        if (lane == 0) {
            rowsig[n * H + h] = wms;       // sigmoid-space (monotone)
            rowmax_b[n * H + h] = wmb;
        }
        // rotate window
        if (j < 3) {
#pragma unroll
            for (int i = 0; i < 8; i++) { A[i] = B[i]; B[i] = C[i]; }
            finishRow(nxtraw, C);
        }
    }

    // column partial maxes for this strip
    const int co = (n * NSTRIP + sid) * W + c0;
    *reinterpret_cast<float4*>(&colpart_s[co]) = make_float4(cms[0], cms[1], cms[2], cms[3]);
    *reinterpret_cast<float4*>(&colpart_b[co]) = make_float4(cmb[0], cmb[1], cmb[2], cmb[3]);

    // per-strip pairwise partials (wave reduce, lane 0 writes)
    const float wst = waveReduceSum(st);
    const float wtt = waveReduceSum(tt);
    if (lane == 0) {
        part_st[strip] = wst;
        part_t[strip] = wtt;
    }
}

// ---------- kernel B: per-image projection loss ----------
__global__ __launch_bounds__(256) void k_proj(
    const float* __restrict__ colpart_s, const float* __restrict__ colpart_b,
    const float* __restrict__ rowsig, const float* __restrict__ rowmax_b,
    float* __restrict__ proj)
{
    __shared__ float red[4];
    const int n = blockIdx.x, t = threadIdx.x;
    float cs = 0.f, cb = 0.f;
#pragma unroll 8
    for (int c = 0; c < NSTRIP; c++) {
        cs = fmaxf(cs, colpart_s[(n * NSTRIP + c) * W + t]);
        cb = fmaxf(cb, colpart_b[(n * NSTRIP + c) * W + t]);
    }
    const float iy = cs;                   // already sigmoid(max x)
    const float ty = cb;
    const float ix = rowsig[n * H + t];
    const float tx = rowmax_b[n * H + t];

    const float Sxy = blockReduceSum(ix * tx, red);
    const float Sxx = blockReduceSum(ix * ix, red);
    const float Stx = blockReduceSum(tx * tx, red);
    const float Syw = blockReduceSum(iy * ty, red);
    const float Syy = blockReduceSum(iy * iy, red);
    const float Sty = blockReduceSum(ty * ty, red);
    if (t == 0) {
        const float eps = 0.001f;
        const float lx = 1.f - 2.f * Sxy / (Sxx + Stx + eps);
        const float ly = 1.f - 2.f * Syw / (Syy + Sty + eps);
        proj[n] = lx + ly;
    }
}

// ---------- kernel C: CE + final combine ----------
__global__ __launch_bounds__(256) void k_final(
    const float* __restrict__ logits, const int* __restrict__ tcls,
    const float* __restrict__ ew, const int* __restrict__ num_masks,
    const float* __restrict__ part_st, const float* __restrict__ part_t,
    const float* __restrict__ proj, float* __restrict__ out)
{
    __shared__ float red[4];
    const int t = threadIdx.x;
    float s1 = 0.f, s2 = 0.f;
    for (int i = t; i < TOTSTRIP; i += 256) { s1 += part_st[i]; s2 += part_t[i]; }
    const float sum_st = blockReduceSum(s1, red);
    const float sum_t = blockReduceSum(s2, red);
    const float pj = (t < NIMG) ? proj[t] : 0.f;
    const float sum_pj = blockReduceSum(pj, red);

    float wn = 0.f, wsum = 0.f;
    if (t < 200) {
        const float* row = logits + t * 81;
        float mx = -3.4e38f;
        for (int c = 0; c < 81; c++) mx = fmaxf(mx, row[c]);
        float se = 0.f;
        for (int c = 0; c < 81; c++) se += expf(row[c] - mx);
        const float lse = mx + logf(se);
        const int tc = tcls[t];
        const float nll = lse - row[tc];
        const float wv = ew[tc];
        wn = wv * nll;
        wsum = wv;
    }
    const float Swn = blockReduceSum(wn, red);
    const float Sw = blockReduceSum(wsum, red);
    if (t == 0) {
        const float nm = (float)max(num_masks[0], 1);
        const float loss_ce = Swn / Sw;
        const float loss_pw = sum_st / fmaxf(sum_t, 1.f) / nm;
        const float loss_pj = sum_pj / nm;
        out[0] = loss_ce + loss_pw + loss_pj;
    }
}

extern "C" void kernel_launch(void* const* d_in, const int* in_sizes, int n_in,
                              void* d_out, int out_size, void* d_ws, size_t ws_size,
                              hipStream_t stream) {
    const float* pred_logits = (const float*)d_in[0];  // [2,100,81]
    const float* src         = (const float*)d_in[1];  // [64,256,256]
    const float* ew          = (const float*)d_in[2];  // [81]
    const float* ts          = (const float*)d_in[3];  // [64,8,256,256]
    const int*   tcls        = (const int*)d_in[4];    // [2,100]
    const int*   bm          = (const int*)d_in[5];    // [64,256,256]
    const int*   nmasks      = (const int*)d_in[6];    // [1]
    float* out = (float*)d_out;

    float* ws = (float*)d_ws;
    float* part_st   = ws;             // 4096
    float* part_t    = ws + 4096;      // 4096
    float* rowsig    = ws + 8192;      // 16384
    float* rowmax_b  = ws + 24576;     // 16384
    float* colpart_s = ws + 40960;     // 64*64*256 = 1048576
    float* colpart_b = ws + 1089536;   // 1048576
    float* proj      = ws + 2138112;   // 64

    k_pairwise<<<dim3(TOTSTRIP / 4), 256, 0, stream>>>(src, ts, bm, part_st, part_t,
                                                       rowsig, rowmax_b, colpart_s, colpart_b);
    k_proj<<<NIMG, 256, 0, stream>>>(colpart_s, colpart_b, rowsig, rowmax_b, proj);
    k_final<<<1, 256, 0, stream>>>(pred_logits, tcls, ew, nmasks, part_st, part_t, proj, out);
}